// Round 1
// baseline (2759.460 us; speedup 1.0000x reference)
//
#include <hip/hip_runtime.h>

// Problem constants (from reference)
constexpr int PT_  = 500000;  // total params
constexpr int KT_  = 398;     // total bases
constexpr int KTP_ = 400;     // padded E row stride (16B-aligned rows)

// ws layout (floats):
//   E        [64*400]      @ 0        (zeroed; atomically accumulated)
//   pNG      [489*64]      @ 25600    (per-block ||G[b]||^2 partials)
//   pNA      [768*64]      @ 56896    (per-block ||approx[b]||^2 partials)
//   w        [398]         @ 106048   (sum_b s_b E[b,k])
//   sRes     [64]          @ 106446

__global__ __launch_bounds__(256) void zero_kernel(float* __restrict__ p, int n) {
    int i = blockIdx.x * 256 + threadIdx.x;
    if (i < n) p[i] = 0.f;
}

// ---------------- Kernel A: E = G @ B (split-K partials via atomics) + ||G[b]||^2 ----------------
template <int KG, int KSLOT, int CP>
__global__ __launch_bounds__(256) void kernelA(const float* __restrict__ G,
                                               const float* __restrict__ Bg,
                                               int Pg, int poff, int koff,
                                               float* __restrict__ E,
                                               float* __restrict__ pNG, int slotBase) {
    __shared__ float Gst[32 * 68];   // [j][b], stride 68 keeps float4 reads aligned + conflict-free
    __shared__ float Bs[32 * KG];    // [j][k] flat (coalesced stage, stride-1 reads)
    const int t  = threadIdx.x;
    const int q  = t >> 6;   // b-quarter 0..3 (wave-uniform -> Gst reads are broadcasts)
    const int kk = t & 63;

    float acc[16][KSLOT];
#pragma unroll
    for (int i = 0; i < 16; i++)
#pragma unroll
        for (int m = 0; m < KSLOT; m++) acc[i][m] = 0.f;

    float vmask[KSLOT];
    int   kidx[KSLOT];
#pragma unroll
    for (int m = 0; m < KSLOT; m++) {
        int k    = kk + 64 * m;
        vmask[m] = (k < KG) ? 1.f : 0.f;
        kidx[m]  = (k < KG) ? k : (KG - 1);
    }

    float ng[8];
#pragma unroll
    for (int r = 0; r < 8; r++) ng[r] = 0.f;

    const int p0 = blockIdx.x * CP;

    for (int jj = 0; jj < CP; jj += 32) {
        __syncthreads();  // protect previous tile's LDS reads
        // stage G tile transposed: Gst[j][b]; also accumulate ||G[b]||^2 partials
#pragma unroll
        for (int r = 0; r < 8; r++) {
            int   idx = t + 256 * r;       // b = (t>>5)+8r fixed per r, j = t&31 fixed
            int   b   = idx >> 5, j = idx & 31;
            int   p   = p0 + jj + j;
            float v   = (p < Pg) ? G[(size_t)b * PT_ + poff + p] : 0.f;
            Gst[j * 68 + b] = v;
            ng[r] += v * v;
        }
        // stage B tile flat (rows contiguous)
        for (int idx = t; idx < 32 * KG; idx += 256) {
            int j = idx / KG, c = idx - j * KG;
            int p = p0 + jj + j;
            Bs[idx] = (p < Pg) ? Bg[(size_t)p * KG + c] : 0.f;
        }
        __syncthreads();
#pragma unroll 2
        for (int j = 0; j < 32; j++) {
            float bv[KSLOT];
#pragma unroll
            for (int m = 0; m < KSLOT; m++) bv[m] = Bs[j * KG + kidx[m]] * vmask[m];
            const float4* gp = reinterpret_cast<const float4*>(&Gst[j * 68 + 16 * q]);
            float4 ga = gp[0], gb = gp[1], gc = gp[2], gd = gp[3];
            float  g[16] = {ga.x, ga.y, ga.z, ga.w, gb.x, gb.y, gb.z, gb.w,
                            gc.x, gc.y, gc.z, gc.w, gd.x, gd.y, gd.z, gd.w};
#pragma unroll
            for (int i = 0; i < 16; i++)
#pragma unroll
                for (int m = 0; m < KSLOT; m++) acc[i][m] += g[i] * bv[m];
        }
    }

    // accumulate partial E (distinct (b,k) per thread within block -> atomics across blocks only)
#pragma unroll
    for (int i = 0; i < 16; i++) {
        int b = 16 * q + i;
#pragma unroll
        for (int m = 0; m < KSLOT; m++) {
            int k = kk + 64 * m;
            if (k < KG) atomicAdd(&E[b * KTP_ + koff + k], acc[i][m]);
        }
    }

    // block-reduce ||G[b]||^2 partials -> deterministic slot write (no global contention)
    __syncthreads();
    if (t < 64) Gst[t] = 0.f;
    __syncthreads();
#pragma unroll
    for (int r = 0; r < 8; r++) atomicAdd(&Gst[(t >> 5) + 8 * r], ng[r]);
    __syncthreads();
    if (t < 64) pNG[(size_t)(slotBase + blockIdx.x) * 64 + t] = Gst[t];
}

// ---------------- Kernel B: ||approx[b]||^2 via on-the-fly (E @ B^T) row-square-sum ----------------
template <int KG, int SB>
__global__ __launch_bounds__(256) void kernelB(const float* __restrict__ Bg,
                                               const float* __restrict__ E,
                                               int Pg, int koff, int nTiles,
                                               float* __restrict__ pNA, int slotBase) {
    __shared__ float Bs[64 * SB];  // 64-row tile, stride SB (padded, (SB/4) odd -> even b128 banking)
    __shared__ float red[64];
    const int t  = threadIdx.x;
    const int q  = t >> 5;   // b-octet 0..7
    const int pp = t & 31;   // p within half-tile; thread covers p0+pp and p0+pp+32

    float pn[8];
#pragma unroll
    for (int i = 0; i < 8; i++) pn[i] = 0.f;

    const float* Erow = E + (8 * q) * KTP_ + koff;  // small, L2-hot, wave-broadcast loads

    for (int tile = blockIdx.x; tile < nTiles; tile += gridDim.x) {
        const int p0 = tile * 64;
        __syncthreads();
        for (int idx = t; idx < 64 * SB; idx += 256) {
            int r = idx / SB, c = idx - r * SB;
            int p = p0 + r;
            Bs[idx] = (c < KG && p < Pg) ? Bg[(size_t)p * KG + c] : 0.f;
        }
        __syncthreads();
        float c0[8], c1[8];
#pragma unroll
        for (int i = 0; i < 8; i++) { c0[i] = 0.f; c1[i] = 0.f; }
        for (int k = 0; k < SB; k += 4) {
            float4 bv0 = *reinterpret_cast<const float4*>(&Bs[pp * SB + k]);
            float4 bv1 = *reinterpret_cast<const float4*>(&Bs[(pp + 32) * SB + k]);
#pragma unroll
            for (int i = 0; i < 8; i++) {
                float4 ev = *reinterpret_cast<const float4*>(&Erow[i * KTP_ + k]);
                c0[i] += ev.x * bv0.x + ev.y * bv0.y + ev.z * bv0.z + ev.w * bv0.w;
                c1[i] += ev.x * bv1.x + ev.y * bv1.y + ev.z * bv1.z + ev.w * bv1.w;
            }
        }
#pragma unroll
        for (int i = 0; i < 8; i++) pn[i] += c0[i] * c0[i] + c1[i] * c1[i];
    }

    __syncthreads();
    if (t < 64) red[t] = 0.f;
    __syncthreads();
#pragma unroll
    for (int i = 0; i < 8; i++) atomicAdd(&red[8 * q + i], pn[i]);
    __syncthreads();
    if (t < 64) pNA[(size_t)(slotBase + blockIdx.x) * 64 + t] = red[t];
}

// ---------------- Kernel C: reduce partials, scales, out0 (avg clipped embedding), w ----------------
__global__ __launch_bounds__(256) void kernelC(const float* __restrict__ pNG, int nNG,
                                               const float* __restrict__ pNA, int nNA,
                                               const float* __restrict__ E,
                                               float* __restrict__ w, float* __restrict__ sRes,
                                               float* __restrict__ out0) {
    __shared__ float red[256];
    __shared__ float ngS[64], naS[64], sEmb[64], sResS[64];
    const int t = threadIdx.x;
    const int b = t & 63, part = t >> 6;

    float acc = 0.f;
    for (int s = part; s < nNG; s += 4) acc += pNG[(size_t)s * 64 + b];
    red[part * 64 + b] = acc;
    __syncthreads();
    if (t < 64) ngS[t] = red[t] + red[64 + t] + red[128 + t] + red[192 + t];
    __syncthreads();

    acc = 0.f;
    for (int s = part; s < nNA; s += 4) acc += pNA[(size_t)s * 64 + b];
    red[part * 64 + b] = acc;
    __syncthreads();
    if (t < 64) naS[t] = red[t] + red[64 + t] + red[128 + t] + red[192 + t];
    __syncthreads();

    acc = 0.f;
    for (int k = part * 100; k < part * 100 + 100; k++) {  // covers 0..399 (pad cols are 0)
        float v = E[b * KTP_ + k];
        acc += v * v;
    }
    red[part * 64 + b] = acc;
    __syncthreads();
    if (t < 64) {
        float ne   = red[t] + red[64 + t] + red[128 + t] + red[192 + t];
        float nrm  = sqrtf(fmaxf(ne, 0.f));
        sEmb[t]    = fminf(1.0f / nrm, 1.0f);   // CLIP0 = 1; 1/0 -> inf -> min = 1 matches ref
        // <G[b], approx[b]> == ||E[b]||^2 exactly (E = G B), so:
        float rn2  = ngS[t] - 2.f * ne + naS[t];
        float rnrm = sqrtf(fmaxf(rn2, 0.f));
        float sv   = fminf(1.0f / rnrm, 1.0f);  // CLIP1 = 1
        sResS[t]   = sv;
        sRes[t]    = sv;
    }
    __syncthreads();

    for (int k = t; k < KT_; k += 256) {
        float e0 = 0.f, wv = 0.f;
        for (int bb = 0; bb < 64; bb++) {
            float v = E[bb * KTP_ + k];
            e0 += sEmb[bb] * v;
            wv += sResS[bb] * v;
        }
        out0[k] = e0 * (1.f / 64.f);
        w[k]    = wv;
    }
}

// ---------------- Kernel D: out1 = (sum_b s_b G[b,p] - sum_k w[k] B[p,k])/64 ; out2 = mean_b G ----------------
template <int KG>
__global__ __launch_bounds__(256) void kernelD(const float* __restrict__ G,
                                               const float* __restrict__ Bg,
                                               const float* __restrict__ w,
                                               const float* __restrict__ sRes,
                                               int Pg, int poff, int koff,
                                               float* __restrict__ out1, float* __restrict__ out2) {
    __shared__ float wS[KG];
    __shared__ float sS[64];
    const int t = threadIdx.x;
    for (int k = t; k < KG; k += 256) wS[k] = w[koff + k];
    if (t < 64) sS[t] = sRes[t];
    __syncthreads();
    int p = blockIdx.x * 256 + t;
    if (p >= Pg) return;
    float a = 0.f, t2 = 0.f;
#pragma unroll 8
    for (int b = 0; b < 64; b++) {
        float g = G[(size_t)b * PT_ + poff + p];
        a  += sS[b] * g;
        t2 += g;
    }
    float dot = 0.f;
    const float* row = Bg + (size_t)p * KG;
#pragma unroll 4
    for (int k = 0; k < KG; k++) dot += wS[k] * row[k];
    out1[poff + p] = (a - dot) * (1.f / 64.f);
    out2[poff + p] = t2 * (1.f / 64.f);
}

extern "C" void kernel_launch(void* const* d_in, const int* in_sizes, int n_in,
                              void* d_out, int out_size, void* d_ws, size_t ws_size,
                              hipStream_t stream) {
    const float* G  = (const float*)d_in[0];
    const float* B0 = (const float*)d_in[1];
    const float* B1 = (const float*)d_in[2];
    const float* B2 = (const float*)d_in[3];
    float* out  = (float*)d_out;
    float* out0 = out;                  // [398]
    float* out1 = out + KT_;            // [500000]
    float* out2 = out + KT_ + PT_;      // [500000]

    float* ws  = (float*)d_ws;
    float* E   = ws;                    // 25600
    float* pNG = ws + 25600;            // 489*64 = 31296
    float* pNA = pNG + 489 * 64;        // 768*64 = 49152
    float* w   = pNA + 768 * 64;        // 398
    float* sR  = w + KT_;               // 64

    // zero E (ws is poisoned 0xAA before every timed launch)
    zero_kernel<<<100, 256, 0, stream>>>(E, 25600);

    constexpr int CP = 1024;
    // Pass A: embeddings + ||G[b]||^2   (grid = ceil(Pg/CP); slot bases 0/98/318)
    kernelA<104, 2, CP><<<98, 256, 0, stream>>>(G, B0, 100000, 0,      0,   E, pNG, 0);
    kernelA<156, 3, CP><<<220, 256, 0, stream>>>(G, B1, 225000, 100000, 104, E, pNG, 98);
    kernelA<138, 3, CP><<<171, 256, 0, stream>>>(G, B2, 175000, 325000, 260, E, pNG, 318);

    // Pass B: ||approx[b]||^2 (grid-stride, 256 blocks/group; slot bases 0/256/512)
    kernelB<104, 108><<<256, 256, 0, stream>>>(B0, E, 100000, 0,   (100000 + 63) / 64, pNA, 0);
    kernelB<156, 156><<<256, 256, 0, stream>>>(B1, E, 225000, 104, (225000 + 63) / 64, pNA, 256);
    kernelB<138, 140><<<256, 256, 0, stream>>>(B2, E, 175000, 260, (175000 + 63) / 64, pNA, 512);

    // Pass C: scales + avg clipped embedding + w
    kernelC<<<1, 256, 0, stream>>>(pNG, 489, pNA, 768, E, w, sR, out0);

    // Pass D: avg clipped residual + avg target grad
    kernelD<104><<<(100000 + 255) / 256, 256, 0, stream>>>(G, B0, w, sR, 100000, 0,      0,   out1, out2);
    kernelD<156><<<(225000 + 255) / 256, 256, 0, stream>>>(G, B1, w, sR, 225000, 100000, 104, out1, out2);
    kernelD<138><<<(175000 + 255) / 256, 256, 0, stream>>>(G, B2, w, sR, 175000, 325000, 260, out1, out2);
}

// Round 2
// 1673.888 us; speedup vs baseline: 1.6485x; 1.6485x over previous
//
#include <hip/hip_runtime.h>

// Problem constants (from reference)
constexpr int PT_  = 500000;  // total params
constexpr int KT_  = 398;     // total bases
constexpr int KTP_ = 400;     // padded E row stride (16B-aligned rows)

// ws layout (floats):
//   E    [64*400]  @ 0       (zeroed; atomically accumulated)
//   NG   [64]      @ 25600   (||G[b]||^2, atomic)
//   NA   [64]      @ 25664   (||approx[b]||^2, atomic)
//   w    [398]     @ 25728
//   sRes [64]      @ 26126

__global__ __launch_bounds__(256) void zero_kernel(float* __restrict__ p, int n) {
    int i = blockIdx.x * 256 + threadIdx.x;
    if (i < n) p[i] = 0.f;
}

// ---------------- Kernel A: E = G @ B (split-K partials via atomics) + ||G[b]||^2 ----------------
template <int KG, int KSLOT, int CP>
__global__ __launch_bounds__(256) void kernelA(const float* __restrict__ G,
                                               const float* __restrict__ Bg,
                                               int Pg, int poff, int koff,
                                               float* __restrict__ E,
                                               float* __restrict__ NG) {
    __shared__ float Gst[32 * 68];   // [j][b], stride 68: float4-aligned, conflict-free
    __shared__ float Bs[32 * KG];    // [j][k] flat
    const int t  = threadIdx.x;
    const int q  = t >> 6;   // b-quarter (wave-uniform -> Gst b128 reads broadcast)
    const int kk = t & 63;

    float acc[16][KSLOT];
#pragma unroll
    for (int i = 0; i < 16; i++)
#pragma unroll
        for (int m = 0; m < KSLOT; m++) acc[i][m] = 0.f;

    float vmask[KSLOT];
    int   kidx[KSLOT];
#pragma unroll
    for (int m = 0; m < KSLOT; m++) {
        int k    = kk + 64 * m;
        vmask[m] = (k < KG) ? 1.f : 0.f;
        kidx[m]  = (k < KG) ? k : (KG - 1);
    }

    float ng[8];
#pragma unroll
    for (int r = 0; r < 8; r++) ng[r] = 0.f;

    const int p0 = blockIdx.x * CP;

    for (int jj = 0; jj < CP; jj += 32) {
        __syncthreads();
#pragma unroll
        for (int r = 0; r < 8; r++) {
            int   idx = t + 256 * r;       // j = t&31 fixed, b = (t>>5)+8r
            int   b   = idx >> 5, j = idx & 31;
            int   p   = p0 + jj + j;
            float v   = (p < Pg) ? G[(size_t)b * PT_ + poff + p] : 0.f;
            Gst[j * 68 + b] = v;
            ng[r] += v * v;
        }
        for (int idx = t; idx < 32 * KG; idx += 256) {
            int j = idx / KG, c = idx - j * KG;
            int p = p0 + jj + j;
            Bs[idx] = (p < Pg) ? Bg[(size_t)p * KG + c] : 0.f;
        }
        __syncthreads();
#pragma unroll 2
        for (int j = 0; j < 32; j++) {
            float bv[KSLOT];
#pragma unroll
            for (int m = 0; m < KSLOT; m++) bv[m] = Bs[j * KG + kidx[m]] * vmask[m];
            const float4* gp = reinterpret_cast<const float4*>(&Gst[j * 68 + 16 * q]);
            float4 ga = gp[0], gb = gp[1], gc = gp[2], gd = gp[3];
            float  g[16] = {ga.x, ga.y, ga.z, ga.w, gb.x, gb.y, gb.z, gb.w,
                            gc.x, gc.y, gc.z, gc.w, gd.x, gd.y, gd.z, gd.w};
#pragma unroll
            for (int i = 0; i < 16; i++)
#pragma unroll
                for (int m = 0; m < KSLOT; m++) acc[i][m] += g[i] * bv[m];
        }
    }

#pragma unroll
    for (int i = 0; i < 16; i++) {
        int b = 16 * q + i;
#pragma unroll
        for (int m = 0; m < KSLOT; m++) {
            int k = kk + 64 * m;
            if (k < KG) atomicAdd(&E[b * KTP_ + koff + k], acc[i][m]);
        }
    }

    __syncthreads();
    if (t < 64) Gst[t] = 0.f;
    __syncthreads();
#pragma unroll
    for (int r = 0; r < 8; r++) atomicAdd(&Gst[(t >> 5) + 8 * r], ng[r]);
    __syncthreads();
    if (t < 64) atomicAdd(&NG[t], Gst[t]);
}

// ---------------- Kernel B: ||approx[b]||^2 via on-the-fly (E @ B^T) row-square-sum ----------------
template <int KG, int SB>
__global__ __launch_bounds__(256) void kernelB(const float* __restrict__ Bg,
                                               const float* __restrict__ E,
                                               int Pg, int koff, int nTiles,
                                               float* __restrict__ NA) {
    __shared__ float Bs[64 * SB];
    __shared__ float red[64];
    const int t  = threadIdx.x;
    const int q  = t >> 5;   // b-octet 0..7
    const int pp = t & 31;

    float pn[8];
#pragma unroll
    for (int i = 0; i < 8; i++) pn[i] = 0.f;

    const float* Erow = E + (8 * q) * KTP_ + koff;

    for (int tile = blockIdx.x; tile < nTiles; tile += gridDim.x) {
        const int p0 = tile * 64;
        __syncthreads();
        for (int idx = t; idx < 64 * SB; idx += 256) {
            int r = idx / SB, c = idx - r * SB;
            int p = p0 + r;
            Bs[idx] = (c < KG && p < Pg) ? Bg[(size_t)p * KG + c] : 0.f;
        }
        __syncthreads();
        float c0[8], c1[8];
#pragma unroll
        for (int i = 0; i < 8; i++) { c0[i] = 0.f; c1[i] = 0.f; }
        for (int k = 0; k < SB; k += 4) {
            float4 bv0 = *reinterpret_cast<const float4*>(&Bs[pp * SB + k]);
            float4 bv1 = *reinterpret_cast<const float4*>(&Bs[(pp + 32) * SB + k]);
#pragma unroll
            for (int i = 0; i < 8; i++) {
                float4 ev = *reinterpret_cast<const float4*>(&Erow[i * KTP_ + k]);
                c0[i] += ev.x * bv0.x + ev.y * bv0.y + ev.z * bv0.z + ev.w * bv0.w;
                c1[i] += ev.x * bv1.x + ev.y * bv1.y + ev.z * bv1.z + ev.w * bv1.w;
            }
        }
#pragma unroll
        for (int i = 0; i < 8; i++) pn[i] += c0[i] * c0[i] + c1[i] * c1[i];
    }

    __syncthreads();
    if (t < 64) red[t] = 0.f;
    __syncthreads();
#pragma unroll
    for (int i = 0; i < 8; i++) atomicAdd(&red[8 * q + i], pn[i]);
    __syncthreads();
    if (t < 64) atomicAdd(&NA[t], red[t]);
}

// ---------------- Kernel C: scales, out0 (avg clipped embedding), w ----------------
__global__ __launch_bounds__(256) void kernelC(const float* __restrict__ NG,
                                               const float* __restrict__ NA,
                                               const float* __restrict__ E,
                                               float* __restrict__ w, float* __restrict__ sRes,
                                               float* __restrict__ out0) {
    __shared__ float red[256];
    __shared__ float sEmb[64], sResS[64];
    const int t = threadIdx.x;
    const int b = t & 63, part = t >> 6;

    float acc = 0.f;
    for (int k = part * 100; k < part * 100 + 100; k++) {  // pad cols 398/399 are 0
        float v = E[b * KTP_ + k];
        acc += v * v;
    }
    red[part * 64 + b] = acc;
    __syncthreads();
    if (t < 64) {
        float ne   = red[t] + red[64 + t] + red[128 + t] + red[192 + t];
        float nrm  = sqrtf(fmaxf(ne, 0.f));
        sEmb[t]    = fminf(1.0f / nrm, 1.0f);   // CLIP0 = 1
        // <G[b], approx[b]> == ||E[b]||^2 exactly (E = G B):
        float rn2  = NG[t] - 2.f * ne + NA[t];
        float rnrm = sqrtf(fmaxf(rn2, 0.f));
        float sv   = fminf(1.0f / rnrm, 1.0f);  // CLIP1 = 1
        sResS[t]   = sv;
        sRes[t]    = sv;
    }
    __syncthreads();

    for (int k = t; k < KT_; k += 256) {
        float e0 = 0.f, wv = 0.f;
        for (int bb = 0; bb < 64; bb++) {
            float v = E[bb * KTP_ + k];
            e0 += sEmb[bb] * v;
            wv += sResS[bb] * v;
        }
        out0[k] = e0 * (1.f / 64.f);
        w[k]    = wv;
    }
}

// ---------------- Kernel D: out1 = (sum_b s_b G[b,p] - sum_k w[k] B[p,k])/64 ; out2 = mean_b G ----------------
// Block handles 64 p-columns; B tile staged in LDS (coalesced); 4 threads cooperate per p.
template <int KG>
__global__ __launch_bounds__(256) void kernelD(const float* __restrict__ G,
                                               const float* __restrict__ Bg,
                                               const float* __restrict__ w,
                                               const float* __restrict__ sRes,
                                               int Pg, int poff, int koff,
                                               float* __restrict__ out1, float* __restrict__ out2) {
    constexpr int LDB = KG + 1;           // odd stride -> conflict-free column reads
    constexpr int KQ  = (KG + 3) / 4;     // k-chunk per part
    __shared__ float Bt[64 * LDB];
    __shared__ float wS[KG];
    __shared__ float sS[64];
    __shared__ float redA[256], redT[256], redD[256];
    const int t    = threadIdx.x;
    const int pidx = t & 63, part = t >> 6;
    const int p0   = blockIdx.x * 64;

    for (int k = t; k < KG; k += 256) wS[k] = w[koff + k];
    if (t < 64) sS[t] = sRes[t];
    for (int idx = t; idx < 64 * KG; idx += 256) {
        int r = idx / KG, c = idx - r * KG;
        int p = p0 + r;
        Bt[r * LDB + c] = (p < Pg) ? Bg[(size_t)p * KG + c] : 0.f;
    }
    __syncthreads();

    const int p = p0 + pidx;
    float a = 0.f, t2 = 0.f, dot = 0.f;
    if (p < Pg) {
#pragma unroll
        for (int bi = 0; bi < 16; bi++) {
            int   b = part * 16 + bi;
            float g = G[(size_t)b * PT_ + poff + p];
            a  += sS[b] * g;
            t2 += g;
        }
        const int k1 = (part * KQ + KQ < KG) ? (part * KQ + KQ) : KG;
        for (int k = part * KQ; k < k1; k++) dot += wS[k] * Bt[pidx * LDB + k];
    }
    redA[t] = a; redT[t] = t2; redD[t] = dot;
    __syncthreads();
    if (part == 0 && p < Pg) {
        float A = redA[t] + redA[64 + t] + redA[128 + t] + redA[192 + t];
        float T = redT[t] + redT[64 + t] + redT[128 + t] + redT[192 + t];
        float D = redD[t] + redD[64 + t] + redD[128 + t] + redD[192 + t];
        out1[poff + p] = (A - D) * (1.f / 64.f);
        out2[poff + p] = T * (1.f / 64.f);
    }
}

extern "C" void kernel_launch(void* const* d_in, const int* in_sizes, int n_in,
                              void* d_out, int out_size, void* d_ws, size_t ws_size,
                              hipStream_t stream) {
    const float* G  = (const float*)d_in[0];
    const float* B0 = (const float*)d_in[1];
    const float* B1 = (const float*)d_in[2];
    const float* B2 = (const float*)d_in[3];
    float* out  = (float*)d_out;
    float* out0 = out;                  // [398]
    float* out1 = out + KT_;            // [500000]
    float* out2 = out + KT_ + PT_;      // [500000]

    float* ws = (float*)d_ws;
    float* E  = ws;                     // 25600
    float* NG = ws + 25600;             // 64
    float* NA = NG + 64;                // 64
    float* w  = NA + 64;                // 398
    float* sR = w + KT_;                // 64

    // zero E + NG + NA (ws is poisoned 0xAA before every timed launch)
    zero_kernel<<<101, 256, 0, stream>>>(E, 25728);

    constexpr int CP = 512;
    // Pass A: embeddings + ||G[b]||^2 — 978 blocks total (~4 co-resident/CU, LDS caps at 5)
    kernelA<104, 2, CP><<<196, 256, 0, stream>>>(G, B0, 100000, 0,      0,   E, NG);
    kernelA<156, 3, CP><<<440, 256, 0, stream>>>(G, B1, 225000, 100000, 104, E, NG);
    kernelA<138, 3, CP><<<342, 256, 0, stream>>>(G, B2, 175000, 325000, 260, E, NG);

    // Pass B: ||approx[b]||^2 — 1024 blocks = 4/CU at 40 KB LDS
    kernelB<104, 108><<<1024, 256, 0, stream>>>(B0, E, 100000, 0,   (100000 + 63) / 64, NA);
    kernelB<156, 156><<<1024, 256, 0, stream>>>(B1, E, 225000, 104, (225000 + 63) / 64, NA);
    kernelB<138, 140><<<1024, 256, 0, stream>>>(B2, E, 175000, 260, (175000 + 63) / 64, NA);

    // Pass C: scales + avg clipped embedding + w
    kernelC<<<1, 256, 0, stream>>>(NG, NA, E, w, sR, out0);

    // Pass D: avg clipped residual + avg target grad (64 p per block, LDS-staged B)
    kernelD<104><<<(100000 + 63) / 64, 256, 0, stream>>>(G, B0, w, sR, 100000, 0,      0,   out1, out2);
    kernelD<156><<<(225000 + 63) / 64, 256, 0, stream>>>(G, B1, w, sR, 225000, 100000, 104, out1, out2);
    kernelD<138><<<(175000 + 63) / 64, 256, 0, stream>>>(G, B2, w, sR, 175000, 325000, 260, out1, out2);
}